// Round 3
// baseline (464.650 us; speedup 1.0000x reference)
//
#include <hip/hip_runtime.h>
#include <math.h>

// Problem constants
#define NF 5
#define NB 8
#define NC 64
#define HW 16384
#define NK 320          // NF*NC
#define FSTRIDE (NB*NC*HW)   // elements per frame = 8388608

// ws layout (floats)
#define EN_FLOATS    (NB*NC*8)   // 4096: per (b,c): E0..E3, N0..N3
#define ALPHA_FLOATS (NB*NK)     // 2560
#define OT_STRIDE 65             // LDS row stride: bank = (65c + s)%32 = (c+s)%32 -> conflict-free

// ---------------- k0: transpose origin_w [64][320] -> Wt [320][64] ----------------
__global__ void k0_wt(const float* __restrict__ W, float* __restrict__ Wt){
    int idx = blockIdx.x*256 + threadIdx.x;
    if (idx < NC*NK){
        int c = idx / NK;
        int k = idx - c*NK;
        Wt[k*NC + c] = W[idx];   // Wt row k = 64 contiguous c -> s_load friendly
    }
}

// ---------------- k1: fused GEMM + E/N reduction, wave-independent ----------------
// grid = 512 blocks x 256 thr; wave w handles tile t = blk*4+w (64 spatial positions).
// Phase A (GEMM): lane = s. acc[c] = bias[c] + sum_k Wt[k][c]*X[k,s].
//   W is wave-uniform -> SGPR; X loads 1 dword/lane, coalesced, read once.
// Phase B: per c-half, transpose o through a per-wave 8.3KB LDS buffer
//   (FULLY UNROLLED h: all acc[] indices compile-time const -> stays in VGPRs;
//    round-2's `#pragma unroll 1` here demoted acc[] to scratch: VGPR=60,
//    WRITE_SIZE=121MB of spill traffic), lane = (c_local, s_half),
//   re-read X rows (L3-resident), accumulate E/N, shfl-combine, atomicAdd.
__global__ __launch_bounds__(256, 4) void k1_fused(
    const float* __restrict__ inp, const float* __restrict__ Wt,
    const float* __restrict__ bias, float* __restrict__ EN)
{
    __shared__ float oT[4][32*OT_STRIDE];   // per-wave private buffers, 33.3 KB total

    const int tid  = threadIdx.x;
    const int w    = tid >> 6;
    const int lane = tid & 63;
    const int t    = blockIdx.x*4 + w;      // 0..2047
    const int b    = t >> 8;                // 256 tiles per batch
    const int s0   = (t & 255) << 6;        // tile base spatial
    float* obuf = oT[w];

    // ---- Phase A: GEMM into acc[64] ----
    float acc[64];
#pragma unroll
    for (int c=0; c<64; ++c) acc[c] = bias[c];          // uniform -> s_load

    for (int f=0; f<NF; ++f){
        const float* fb = inp + (size_t)(f*NB + b)*NC*HW + s0 + lane;
        const float* wr = Wt + f*64*NC;
#pragma unroll 4
        for (int k=0; k<64; ++k){
            float x = fb[(size_t)k*HW];                 // coalesced, 256B/wave
#pragma unroll
            for (int c=0; c<64; ++c)
                acc[c] = fmaf(wr[k*NC + c], x, acc[c]); // W uniform -> scalar operand
        }
    }

    // ---- Phase B: E/N accumulation ----
    const int cl = lane & 31;       // c within half
    const int sh = lane >> 5;       // s-half
    float accE[2][4], accN[2][4];
#pragma unroll
    for (int h=0; h<2; ++h)
#pragma unroll
        for (int i=0; i<4; ++i){ accE[h][i]=0.f; accN[h][i]=0.f; }

#pragma unroll
    for (int h=0; h<2; ++h){        // MUST fully unroll: keeps acc[] constant-indexed
        // transpose-write this c-half: lane s writes o[h*32+j] to LDS row j
        // addr = j*65 + lane -> banks (j+lane)%32: conflict-free
#pragma unroll
        for (int j=0; j<32; ++j)
            obuf[j*OT_STRIDE + lane] = acc[h*32 + j];
        // same-wave RAW through LDS: compiler inserts lgkmcnt wait; no barrier needed

        const int c = h*32 + cl;
        const float* orow = obuf + cl*OT_STRIDE + sh*32;
        const float* base = inp + ((size_t)b*NC + c)*HW + s0 + sh*32;
        const float* x4r  = base + (size_t)4*FSTRIDE;

#pragma unroll
        for (int j4=0; j4<8; ++j4){
            float4 x4 = *reinterpret_cast<const float4*>(x4r + j4*4);
            float o0 = orow[j4*4+0], o1 = orow[j4*4+1];
            float o2 = orow[j4*4+2], o3 = orow[j4*4+3];
#pragma unroll
            for (int i=0; i<4; ++i){
                float4 xi = *reinterpret_cast<const float4*>(base + (size_t)i*FSTRIDE + j4*4);
                float d0 = x4.x-xi.x, d1 = x4.y-xi.y, d2 = x4.z-xi.z, d3 = x4.w-xi.w;
                accN[h][i] = fmaf(d0,d0, fmaf(d1,d1, fmaf(d2,d2, fmaf(d3,d3, accN[h][i]))));
                accE[h][i] = fmaf(o0,d0, fmaf(o1,d1, fmaf(o2,d2, fmaf(o3,d3, accE[h][i]))));
            }
        }
    }

    // combine the two s-halves (lanes l and l+32 hold same (c,i))
#pragma unroll
    for (int h=0; h<2; ++h)
#pragma unroll
        for (int i=0; i<4; ++i){
            accE[h][i] += __shfl_xor(accE[h][i], 32, 64);
            accN[h][i] += __shfl_xor(accN[h][i], 32, 64);
        }

    if (lane < 32){
        float* enb = EN + (size_t)b*NC*8;
#pragma unroll
        for (int h=0; h<2; ++h){
            int c = h*32 + cl;
#pragma unroll
            for (int i=0; i<4; ++i){
                atomicAdd(&enb[c*8 + i],     accE[h][i]);
                atomicAdd(&enb[c*8 + 4 + i], accN[h][i]);
            }
        }
    }
}

// ---------------- k2: finalize coef -> alpha ----------------
__global__ void k2_coef(const float* __restrict__ EN, const float* __restrict__ out_w,
                        float* __restrict__ alpha)
{
    int tid = threadIdx.x;          // 512 = NB*NC
    int b = tid >> 6, c = tid & 63;
    const float* e = EN + (b*NC + c)*8;
    float w1 = out_w[c], w2 = out_w[NC + c];
    float csum = 0.f;
#pragma unroll
    for (int i=0; i<4; ++i){
        float n = fmaxf(sqrtf(e[4+i]), 1e-12f);
        float coef = e[i] / (n*n);
        alpha[b*NK + i*NC + c] = -w1*coef;
        csum += coef;
    }
    alpha[b*NK + 4*NC + c] = w1*csum + w2;
}

// ---------------- k3: y[b,s] = sum_r alpha[b,r]*inp[r,b,s] + out_b ----------------
// float4 per thread: 16B/lane loads (1KB/wave-inst), 320 independent loads deep.
__global__ __launch_bounds__(256) void k3_out(const float* __restrict__ inp,
        const float* __restrict__ alpha, const float* __restrict__ out_b,
        float* __restrict__ y)
{
    int b = blockIdx.x >> 4;                      // 16 blocks per batch
    int s = (((blockIdx.x & 15) << 8) + threadIdx.x) << 2;
    const float* al = alpha + b*NK;               // wave-uniform -> s_load
    float bb = out_b[0];
    float4 a = make_float4(bb, bb, bb, bb);
    const float* base = inp + (size_t)b*NC*HW + s;
#pragma unroll
    for (int f=0; f<NF; ++f){
        const float* fb = base + (size_t)f*FSTRIDE;
#pragma unroll 8
        for (int c=0; c<NC; ++c){
            float4 v = *reinterpret_cast<const float4*>(fb + (size_t)c*HW);
            float wv = al[f*NC + c];
            a.x = fmaf(wv, v.x, a.x);
            a.y = fmaf(wv, v.y, a.y);
            a.z = fmaf(wv, v.z, a.z);
            a.w = fmaf(wv, v.w, a.w);
        }
    }
    *reinterpret_cast<float4*>(y + (size_t)b*HW + s) = a;
}

extern "C" void kernel_launch(void* const* d_in, const int* in_sizes, int n_in,
                              void* d_out, int out_size, void* d_ws, size_t ws_size,
                              hipStream_t stream)
{
    const float* inp      = (const float*)d_in[0];
    const float* origin_w = (const float*)d_in[1];
    const float* origin_b = (const float*)d_in[2];
    const float* out_w    = (const float*)d_in[3];
    const float* out_b    = (const float*)d_in[4];
    float* y  = (float*)d_out;
    float* ws = (float*)d_ws;

    float* EN    = ws;                              // 4096 floats
    float* alpha = ws + EN_FLOATS;                  // 2560 floats
    float* Wt    = ws + EN_FLOATS + ALPHA_FLOATS;   // 20480 floats

    hipMemsetAsync(EN, 0, EN_FLOATS*sizeof(float), stream);
    k0_wt   <<<(NC*NK + 255)/256, 256, 0, stream>>>(origin_w, Wt);
    k1_fused<<<512, 256, 0, stream>>>(inp, Wt, origin_b, EN);
    k2_coef <<<1, NB*NC, 0, stream>>>(EN, out_w, alpha);
    k3_out  <<<NB*16, 256, 0, stream>>>(inp, alpha, out_b, y);
}